// Round 6
// baseline (180.165 us; speedup 1.0000x reference)
//
#include <hip/hip_runtime.h>
#include <hip/hip_fp16.h>
#include <math.h>

// Model: review-based recommender. ALL float tensors fp32.
// Shapes: VOCAB=20000, D=100, H=100, K=3, N_U=N_I=256, R=8, S=52, Sp=50, E=20000.
// Outputs (fp32, flat): pred_r[20000] @0, pred_c[20000] @20000,
//                       z_u[102400] @40000, z_i[102400] @142400.
//
// R20: k_branch LDS 39840 -> 28896 B to unlock 5 blocks/CU (was LDS-capped at
// 4 = 16 waves = 50%; measured occupancy sat exactly at that cap, with ~50%
// of cycles issuing on no pipe => latency-bound). (a) xw compacted 2x6656 ->
// 2x5328 shorts: dummy A-rows 50..63 clamp to row 50 (one min per thread,
// outside all loops; their acc output was always masked), zero pad only
// flat[5200..5327] (max real read: row49,kt9 -> 5220). (b) epilogue scratch
// (s_vmax/s_maxf/s_z/s_lg/s_P, 5632B) overlays wbuf, dead after the kt=9
// barrier. K-loop/epilogue logic otherwise byte-identical to R16/R19.
// k_prep/k_refine/k_gmat(R18 MFMA)/k_edge identical to R19.

typedef __attribute__((ext_vector_type(8))) _Float16 half8;
typedef __attribute__((ext_vector_type(4))) float f32x4;

__device__ __forceinline__ float sigmoidf_(float x) { return 1.f / (1.f + expf(-x)); }
__device__ __forceinline__ ushort f2h(float x) {
    union { __half h; ushort u; } t; t.h = __float2half(x); return t.u;
}
__device__ __forceinline__ float h2f(ushort u) {
    union { __half h; ushort u; } t; t.u = u; return __half2float(t.h);
}

#define Z_MARGIN 4e-4f
#define FLAG_CAP 204800

// ---------------------------------------------------------------------------
// K0: prep: Wt[kk=300][h=100] fp32 (refine); fc2t[h][dd]; zero Psum;
// wpack f16 B-frag layout (verified r10/r11); zero flag cnt; emb -> f16 (x4 vec).
__global__ void k_prep(const float* __restrict__ conv_w, const float* __restrict__ fc_w2_w,
                       const float* __restrict__ emb,
                       float* __restrict__ Wt, float* __restrict__ fc2t,
                       float* __restrict__ Psum, ushort* __restrict__ wpack,
                       int* __restrict__ flag_cnt, ushort* __restrict__ emb16) {
    int idx = blockIdx.x * 256 + threadIdx.x;
    if (idx < 30000) {
        int kk = idx / 100, h = idx - kk * 100;
        Wt[idx] = conv_w[h * 300 + kk];
    } else if (idx < 40000) {
        int j = idx - 30000;
        int h = j / 100, dd = j - h * 100;
        fc2t[j] = fc_w2_w[dd * 100 + h];
    } else if (idx < 91200) {
        Psum[idx - 40000] = 0.f;
    } else if (idx < 127040) {
        int j = idx - 91200;                   // [0, 35840)
        int frag = j >> 9, within = j & 511;
        int l = within >> 3, jj = within & 7;
        int kt = frag / 7, nt = frag % 7;
        int kk = kt * 32 + ((l >> 4) << 3) + jj;
        int h  = nt * 16 + (l & 15);
        wpack[j] = (kk < 300 && h < 100) ? f2h(conv_w[h * 300 + kk]) : (ushort)0;
    } else if (idx == 127040) {
        *flag_cnt = 0;
    } else {
        int j = idx - 127041;                  // [0, 500000) float4 groups
        if (j < 500000) {
            float4 v = ((const float4*)emb)[j];
            uint2 o;
            o.x = (unsigned)f2h(v.x) | ((unsigned)f2h(v.y) << 16);
            o.y = (unsigned)f2h(v.z) | ((unsigned)f2h(v.w) << 16);
            ((uint2*)emb16)[j] = o;
        }
    }
}

// ---------------------------------------------------------------------------
// K1: 2 instances per block (grid 2048), 256 threads = 4 waves, wave = m-tile
// for BOTH instances. Cooperative LDS W staging; each B frag ds_read feeds
// acc0 and acc1. R20: compact xw (row clamp) + epilogue-over-wbuf overlay;
// LDS 28896 B -> 5 blocks/CU.
__global__ __launch_bounds__(256, 4)
void k_branch(const int* __restrict__ u_rev, const int* __restrict__ i_rev,
              const ushort* __restrict__ emb16, const ushort* __restrict__ wpack,
              const float* __restrict__ conv_b, const float* __restrict__ fc_w_w,
              const float* __restrict__ fc_w_b, const float* __restrict__ fc_w2_b,
              const float* __restrict__ fc2t, const float* __restrict__ h_r_w,
              const float* __restrict__ h_c_w,
              float* __restrict__ Pbuf, float* __restrict__ Psum,
              float* __restrict__ zdot, float* __restrict__ Pdot,
              float* __restrict__ z_out, int* __restrict__ flag_cnt,
              int* __restrict__ flag_list) {
    __shared__ __align__(16) char smem[28896];
    ushort* xw    = (ushort*)smem;                   // [2][5328] f16 X flat (+128 zero pad)
    ushort* wbuf  = (ushort*)(smem + 21312);         // [3584] one kt-chunk B-frags
    // epilogue scratch overlays wbuf (dead after kt=9 barrier):
    float*  s_vmax= (float*)(smem + 21312);          // [2][4][100]
    float*  s_maxf= (float*)(smem + 24512);          // [2][100]
    float*  s_z   = (float*)(smem + 25312);          // [2][52]
    float*  s_lg  = (float*)(smem + 25728);          // [2][52]
    float*  s_P   = (float*)(smem + 26144);          // [2][100]
    int*    s_tok = (int*)(smem + 28480);            // [2][52]

    const int tid = threadIdx.x, lane = tid & 63, w = tid >> 6;
    const int b = blockIdx.x;
    const int branch = b >> 10, pair = b & 1023;
    const int inst0 = pair * 2;

    const uint4* wp4 = (const uint4*)wpack;
    uint4* wbuf4 = (uint4*)wbuf;
    uint4 st0 = wp4[tid];
    uint4 st1; if (tid < 192) st1 = wp4[256 + tid];

    const int* rev = branch ? i_rev : u_rev;
    if (tid < 104) {
        int ii = tid >= 52, s = tid - ii * 52;
        s_tok[tid] = rev[(inst0 + ii) * 52 + s];
    }
    __syncthreads();

    {
        const uint2* emb2 = (const uint2*)emb16;
        uint2 v[11];
#pragma unroll
        for (int k = 0; k < 11; k++) {
            int idx = tid + (k << 8);
            if (idx < 2600) {
                int ii = idx >= 1300;
                int within = idx - ii * 1300;
                int s = within / 25, c = within - s * 25;
                v[k] = emb2[s_tok[ii * 52 + s] * 25 + c];
            }
        }
#pragma unroll
        for (int k = 0; k < 11; k++) {
            int idx = tid + (k << 8);
            if (idx < 2600) {
                int ii = idx >= 1300;
                int within = idx - ii * 1300;
                *(uint2*)(xw + ii * 5328 + within * 4) = v[k];
            }
        }
        // zero pad: shorts [5200,5328) per instance = 16 uint4 each
        if (tid < 32) {
            uint4 z4; z4.x = 0u; z4.y = 0u; z4.z = 0u; z4.w = 0u;
            int ii = tid >= 16, off = tid & 15;
            ((uint4*)xw)[ii * 666 + 650 + off] = z4;
        }
    }

    wbuf4[tid] = st0;
    if (tid < 192) wbuf4[256 + tid] = st1;
    st0 = wp4[448 + tid];
    if (tid < 192) st1 = wp4[448 + 256 + tid];
    __syncthreads();

    f32x4 acc0[7], acc1[7];
#pragma unroll
    for (int nt = 0; nt < 7; nt++) {
        acc0[nt] = (f32x4){0.f, 0.f, 0.f, 0.f};
        acc1[nt] = (f32x4){0.f, 0.f, 0.f, 0.f};
    }

    const int col = lane & 15, quad = lane >> 4, q8 = quad << 3;
    const int mt = w;
    // A-row clamp: rows >= 50 produce masked junk; clamp to row 50 so the
    // compact xw (5328 shorts) covers all reads (max 5320).
    const int arow_ = mt * 16 + col;
    const int arow  = arow_ < 50 ? arow_ : 50;

    for (int kt = 0; kt < 10; kt++) {
        {
            int e0 = arow * 100 + kt * 32 + q8;
            union AU { half8 h8; uint2 u2[2]; } a0, a1;
            a0.u2[0] = *(const uint2*)(xw + e0);
            a0.u2[1] = *(const uint2*)(xw + e0 + 4);
            a1.u2[0] = *(const uint2*)(xw + 5328 + e0);
            a1.u2[1] = *(const uint2*)(xw + 5328 + e0 + 4);
#pragma unroll
            for (int nt = 0; nt < 7; nt++) {
                union BU { half8 h8; uint4 u4; } bu;
                bu.u4 = wbuf4[nt * 64 + lane];
                acc0[nt] = __builtin_amdgcn_mfma_f32_16x16x32_f16(a0.h8, bu.h8, acc0[nt], 0, 0, 0);
                acc1[nt] = __builtin_amdgcn_mfma_f32_16x16x32_f16(a1.h8, bu.h8, acc1[nt], 0, 0, 0);
            }
        }
        __syncthreads();
        if (kt < 9) {
            wbuf4[tid] = st0;
            if (tid < 192) wbuf4[256 + tid] = st1;
            if (kt < 8) {
                st0 = wp4[(kt + 2) * 448 + tid];
                if (tid < 192) st1 = wp4[(kt + 2) * 448 + 256 + tid];
            }
            __syncthreads();
        }
    }
    // NOTE: all waves passed the barrier after the kt=9 MFMA -> wbuf dead;
    // epilogue scratch below lives in the same LDS bytes.

    // epilogue. C/D layout: n=col, m-row = quad*4+j [r6-r11 verified].
    float cb[7], fw[7];
#pragma unroll
    for (int nt = 0; nt < 7; nt++) {
        int h = nt * 16 + col;
        cb[nt] = (h < 100) ? conv_b[h] : 0.f;
        fw[nt] = (h < 100) ? fc_w_w[h] : 0.f;
    }
    const float fcb = fc_w_b[0];

#define EPILOGUE_MM(II, ACC)                                                   \
    {                                                                          \
        float vmax[7];                                                         \
        _Pragma("unroll") for (int nt = 0; nt < 7; nt++) vmax[nt] = 0.f;       \
        _Pragma("unroll")                                                      \
        for (int j = 0; j < 4; j++) {                                          \
            int p = mt * 16 + quad * 4 + j;                                    \
            bool pv = p < 50;                                                  \
            float part = 0.f;                                                  \
            _Pragma("unroll")                                                  \
            for (int nt = 0; nt < 7; nt++) {                                   \
                float c = ACC[nt][j] + cb[nt];                                 \
                c = c > 0.f ? c : 0.f;                                         \
                part += c * fw[nt];                                            \
                if (pv) vmax[nt] = fmaxf(vmax[nt], c);                         \
            }                                                                  \
            part += __shfl_xor(part, 1, 64);                                   \
            part += __shfl_xor(part, 2, 64);                                   \
            part += __shfl_xor(part, 4, 64);                                   \
            part += __shfl_xor(part, 8, 64);                                   \
            if (pv && col == 0) {                                              \
                float logit = part + fcb;                                      \
                float z = rintf(sigmoidf_(logit));                             \
                s_z[(II) * 52 + p] = z;                                        \
                s_lg[(II) * 52 + p] = logit;                                   \
                z_out[branch * 102400 + (inst0 + (II)) * 50 + p] = z;          \
            }                                                                  \
        }                                                                      \
        _Pragma("unroll")                                                      \
        for (int nt = 0; nt < 7; nt++) {                                       \
            float m = vmax[nt];                                                \
            m = fmaxf(m, __shfl_xor(m, 16, 64));                               \
            m = fmaxf(m, __shfl_xor(m, 32, 64));                               \
            int h = nt * 16 + col;                                             \
            if (quad == 0 && h < 100) s_vmax[(II) * 400 + w * 100 + h] = m;    \
        }                                                                      \
    }

    EPILOGUE_MM(0, acc0)
    EPILOGUE_MM(1, acc1)
#undef EPILOGUE_MM
    __syncthreads();

    if (tid < 200) {
        int ii = tid >= 100, h = tid - ii * 100;
        const float* sv = s_vmax + ii * 400;
        float mx = fmaxf(fmaxf(sv[h], sv[100 + h]),
                         fmaxf(sv[200 + h], sv[300 + h]));
        s_maxf[ii * 100 + h] = mx;
    }
    __syncthreads();

    if (tid < 200) {
        int ii = tid >= 100, dd = tid - ii * 100;
        float a = fc_w2_b[dd];
        for (int h0 = 0; h0 < 100; h0 += 10) {
            float wv[10], mxv[10];
#pragma unroll
            for (int t = 0; t < 10; t++) {
                wv[t] = fc2t[(h0 + t) * 100 + dd];
                mxv[t] = s_maxf[ii * 100 + h0 + t];
            }
#pragma unroll
            for (int t = 0; t < 10; t++) a += mxv[t] * wv[t];
        }
        int inst = inst0 + ii;
        int gi = branch * 2048 + inst;
        Pbuf[gi * 100 + dd] = a;
        s_P[ii * 100 + dd] = a;
        atomicAdd(&Psum[(branch * 256 + (inst >> 3)) * 100 + dd], a);
    }
    __syncthreads();

    if (w == 0) {
#pragma unroll
        for (int ii = 0; ii < 2; ii++) {
            float v = (lane < 50) ? s_z[ii * 52 + lane] * h_r_w[branch * 50 + lane] : 0.f;
            for (int s = 1; s < 64; s <<= 1) v += __shfl_xor(v, s, 64);
            if (lane == 0) zdot[branch * 2048 + inst0 + ii] = v;
        }
    } else if (w == 1) {
#pragma unroll
        for (int ii = 0; ii < 2; ii++) {
            float u = 0.f;
            if (lane < 50) u = s_P[ii * 100 + lane] * h_c_w[branch * 100 + lane]
                             + s_P[ii * 100 + lane + 50] * h_c_w[branch * 100 + lane + 50];
            for (int s = 1; s < 64; s <<= 1) u += __shfl_xor(u, s, 64);
            if (lane == 0) Pdot[branch * 2048 + inst0 + ii] = u;
        }
    } else {
        int ii = w - 2;                       // w==2 -> inst0, w==3 -> inst0+1
        float lg = 1e9f;
        if (lane < 50) lg = s_lg[ii * 52 + lane];
        unsigned long long mb = __ballot(fabsf(lg) < Z_MARGIN);
        int cnt = __popcll(mb);
        int base = 0;
        if (lane == 0 && cnt) base = atomicAdd(flag_cnt, cnt);
        base = __shfl(base, 0, 64);
        if (fabsf(lg) < Z_MARGIN) {
            int rank = __popcll(mb & ((1ull << lane) - 1ull));
            int k = base + rank;
            if (k < FLAG_CAP) flag_list[k] = (branch * 2048 + inst0 + ii) * 50 + lane;
        }
    }
}

// ---------------------------------------------------------------------------
// K2: exact fp32 recompute of flagged z-logits (identical to r14-r19).
__launch_bounds__(256)
__global__ void k_refine(const int* __restrict__ u_rev, const int* __restrict__ i_rev,
                         const float* __restrict__ emb, const float* __restrict__ Wt,
                         const float* __restrict__ conv_b, const float* __restrict__ fc_w_w,
                         const float* __restrict__ fc_w_b, const float* __restrict__ h_r_w,
                         const int* __restrict__ flag_cnt, const int* __restrict__ flag_list,
                         float* __restrict__ z_out, float* __restrict__ zdot) {
    int n = *flag_cnt; if (n > FLAG_CAP) n = FLAG_CAP;
    const int lane = threadIdx.x & 63;
    const int wid = (blockIdx.x * 256 + threadIdx.x) >> 6;
    const int nw = gridDim.x * 4;
    const bool hv = lane < 50;
    const float cb0 = hv ? conv_b[lane] : 0.f;
    const float cb1 = hv ? conv_b[lane + 50] : 0.f;
    const float fw0 = hv ? fc_w_w[lane] : 0.f;
    const float fw1 = hv ? fc_w_w[lane + 50] : 0.f;
    const float fcb = fc_w_b[0];

    for (int e0 = wid * 4; e0 < n; e0 += nw * 4) {
        int gi[4], pos[4];
        bool iv[4];
        float xr[4][5];
#pragma unroll
        for (int m = 0; m < 4; m++) {
            int e = e0 + m;
            iv[m] = e < n;
            int code = iv[m] ? flag_list[e] : 0;
            gi[m] = code / 50; pos[m] = code - gi[m] * 50;
            const int* rev = (gi[m] >> 11) ? i_rev : u_rev;
            int tb = (gi[m] & 2047) * 52 + pos[m];
            int t0 = rev[tb], t1 = rev[tb + 1], t2 = rev[tb + 2];
#pragma unroll
            for (int s = 0; s < 5; s++) {
                int k = s * 64 + lane;
                float v = 0.f;
                if (k < 300) {
                    int r = k / 100, dd = k - r * 100;
                    int t = (r == 0) ? t0 : ((r == 1) ? t1 : t2);
                    v = emb[t * 100 + dd];
                }
                xr[m][s] = v;
            }
        }
        float c0[4], c1[4];
#pragma unroll
        for (int m = 0; m < 4; m++) { c0[m] = cb0; c1[m] = cb1; }
        for (int s = 0; s < 5; s++) {
            const int dmax = (s < 4) ? 64 : 44;
            for (int db = 0; db < dmax; db += 16) {
                const int cnt = (dmax - db < 16) ? (dmax - db) : 16;
                float w0a[16], w1a[16];
#pragma unroll
                for (int t = 0; t < 16; t++) {
                    int d = s * 64 + db + t;
                    bool on = (t < cnt) && hv;          // masked: OOB lanes load 0
                    w0a[t] = on ? Wt[d * 100 + lane] : 0.f;
                    w1a[t] = on ? Wt[d * 100 + lane + 50] : 0.f;
                }
#pragma unroll
                for (int t = 0; t < 16; t++) {          // w==0 beyond cnt -> adds 0
#pragma unroll
                    for (int m = 0; m < 4; m++) {
                        float x = __shfl(xr[m][s], db + t, 64);
                        c0[m] += x * w0a[t];
                        c1[m] += x * w1a[t];
                    }
                }
            }
        }
#pragma unroll
        for (int m = 0; m < 4; m++) {
            float v = fmaxf(c0[m], 0.f) * fw0 + fmaxf(c1[m], 0.f) * fw1;
            for (int s = 1; s < 64; s <<= 1) v += __shfl_xor(v, s, 64);
            if (lane == 0 && iv[m]) {
                int branch = gi[m] >> 11, inst = gi[m] & 2047;
                float z = rintf(sigmoidf_(v + fcb));
                float old = z_out[branch * 102400 + inst * 50 + pos[m]];
                if (z != old) {
                    z_out[branch * 102400 + inst * 50 + pos[m]] = z;
                    atomicAdd(&zdot[gi[m]], (z - old) * h_r_w[branch * 50 + pos[m]]);
                }
            }
        }
    }
}

// ---------------------------------------------------------------------------
// K3 (R18): G as MFMA GEMM. G_s[i][j] = dot(PsumSide_s[i], Pbuf_s[j]),
// i in [0,256), j in [0,2048), K=100 (padded 128 with zeros).
// Grid 256: b -> s = b>>7, it = (b>>5)&3 (64 i-rows), jt = b&31 (64 j-rows).
// Both operands f32->f16 into LDS [64][136] (stride 136 breaks pow2 banks),
// then 4 waves x (4 kt x 4 nt) MFMA, D layout n=col / m=quad*4+jj (verified).
__launch_bounds__(256)
__global__ void k_gmat(const float* __restrict__ Pbuf, const float* __restrict__ Psum,
                       ushort* __restrict__ G) {
    __shared__ __align__(16) ushort Af[64 * 136];   // Psum side (i rows)
    __shared__ __align__(16) ushort Bf[64 * 136];   // Pbuf side (j rows)

    const int tid = threadIdx.x, lane = tid & 63, w = tid >> 6;
    const int b = blockIdx.x;
    const int s = b >> 7, it = (b >> 5) & 3, jt = b & 31;
    const int ibase = it * 64, jbase = jt * 64;

    const float4* psum4 = (const float4*)(Psum + (s == 0 ? 25600 : 0) + ibase * 100);
    const float4* pbuf4 = (const float4*)(Pbuf + (s * 2048 + jbase) * 100);

    // stage: 2 tiles x 64 rows x 25 float4 -> f16 LDS (cols 0..100)
    for (int g = tid; g < 3200; g += 256) {
        int side = g >= 1600, within = g - side * 1600;
        int r = within / 25, c4 = within - r * 25;
        float4 v = side ? pbuf4[r * 25 + c4] : psum4[r * 25 + c4];
        uint2 o;
        o.x = (unsigned)f2h(v.x) | ((unsigned)f2h(v.y) << 16);
        o.y = (unsigned)f2h(v.z) | ((unsigned)f2h(v.w) << 16);
        ushort* dst = (side ? Bf : Af) + r * 136 + c4 * 4;
        *(uint2*)dst = o;
    }
    // zero pad cols 100..128 (read by kt=3), both tiles
    for (int t = tid; t < 896; t += 256) {
        int side = t >= 448, within = t - side * 448;
        int r = within / 7, k = within - r * 7;
        ushort* dst = (side ? Bf : Af) + r * 136 + 100 + k * 4;
        *(uint2*)dst = (uint2){0u, 0u};
    }
    __syncthreads();

    const int col = lane & 15, quad = lane >> 4, q8 = quad << 3;

    f32x4 acc[4];
#pragma unroll
    for (int nt = 0; nt < 4; nt++) acc[nt] = (f32x4){0.f, 0.f, 0.f, 0.f};

#pragma unroll
    for (int kt = 0; kt < 4; kt++) {
        union FU { half8 h8; uint4 u4; } a;
        a.u4 = *(const uint4*)(Af + (w * 16 + col) * 136 + kt * 32 + q8);
#pragma unroll
        for (int nt = 0; nt < 4; nt++) {
            union FU bu;
            bu.u4 = *(const uint4*)(Bf + (nt * 16 + col) * 136 + kt * 32 + q8);
            acc[nt] = __builtin_amdgcn_mfma_f32_16x16x32_f16(a.h8, bu.h8, acc[nt], 0, 0, 0);
        }
    }

    // D layout: n (j within 16) = col, m (i within 16) = quad*4+jj
    ushort* Gs = G + s * 524288;
#pragma unroll
    for (int nt = 0; nt < 4; nt++) {
#pragma unroll
        for (int jj = 0; jj < 4; jj++) {
            int gi_row = ibase + w * 16 + quad * 4 + jj;
            int gj = jbase + nt * 16 + col;
            Gs[gi_row * 2048 + gj] = f2h(acc[nt][jj]);
        }
    }
}

// ---------------------------------------------------------------------------
// K4: per-edge, O(1) reads (identical to r11-r19).
__launch_bounds__(256)
__global__ void k_edge(const int* __restrict__ uid, const int* __restrict__ iid,
                       const ushort* __restrict__ G,
                       const float* __restrict__ zdot, const float* __restrict__ Pdot,
                       const float* __restrict__ user_bias, const float* __restrict__ item_bias,
                       const float* __restrict__ global_bias, float* __restrict__ out) {
    const int tid = threadIdx.x, lane = tid & 63, w = tid >> 6;
    const int e = blockIdx.x * 16 + w * 4 + (lane >> 4);
    const int r = lane & 15;
    int u = uid[e], i = iid[e];
    float gv, wr, wc;
    if (r < 8) {
        gv = h2f(G[i * 2048 + u * 8 + r]);
        wr = zdot[u * 8 + r]; wc = Pdot[u * 8 + r];
    } else {
        int a = r - 8;
        gv = h2f(G[524288 + u * 2048 + i * 8 + a]);
        wr = zdot[2048 + i * 8 + a]; wc = Pdot[2048 + i * 8 + a];
    }
    float sg = sigmoidf_(gv);
    float cr = sg * wr, cc = sg * wc;
    cr += __shfl_xor(cr, 1, 64); cc += __shfl_xor(cc, 1, 64);
    cr += __shfl_xor(cr, 2, 64); cc += __shfl_xor(cc, 2, 64);
    cr += __shfl_xor(cr, 4, 64); cc += __shfl_xor(cc, 4, 64);
    cr += __shfl_xor(cr, 8, 64); cc += __shfl_xor(cc, 8, 64);
    if (r == 0) {
        out[e] = cr + user_bias[u] + item_bias[i] + global_bias[0];
        out[20000 + e] = cc;
    }
}

// ---------------------------------------------------------------------------
extern "C" void kernel_launch(void* const* d_in, const int* in_sizes, int n_in,
                              void* d_out, int out_size, void* d_ws, size_t ws_size,
                              hipStream_t stream) {
    const int*   u_rev    = (const int*)d_in[0];
    const int*   i_rev    = (const int*)d_in[1];
    const int*   uid      = (const int*)d_in[2];
    const int*   iid      = (const int*)d_in[3];
    const float* emb      = (const float*)d_in[4];
    const float* conv_w   = (const float*)d_in[5];
    const float* conv_b   = (const float*)d_in[6];
    const float* fc_w_w   = (const float*)d_in[7];
    const float* fc_w_b   = (const float*)d_in[8];
    const float* fc_w2_w  = (const float*)d_in[9];
    const float* fc_w2_b  = (const float*)d_in[10];
    const float* h_r_w    = (const float*)d_in[11];
    const float* h_c_w    = (const float*)d_in[12];
    const float* user_b   = (const float*)d_in[13];
    const float* item_b   = (const float*)d_in[14];
    const float* global_b = (const float*)d_in[15];
    float* out = (float*)d_out;

    float*  ws    = (float*)d_ws;
    float*  Pbuf  = ws;                       // [409600]
    float*  Psum  = ws + 409600;              // [51200]
    float*  zdotb = ws + 460800;              // [4096]
    float*  Pdotb = ws + 464896;              // [4096]
    float*  Wt    = ws + 468992;              // [30000]
    float*  fc2t  = ws + 498992;              // [10000]
    ushort* wpack = (ushort*)(ws + 508992);   // [35840] f16
    int*    flagc = (int*)(ws + 526912);      // [1]
    int*    flist = (int*)(ws + 526916);      // [204800]
    ushort* emb16 = (ushort*)(ws + 731716);   // [2,000,000] f16
    ushort* Gbuf  = (ushort*)(ws + 1731716);  // [2][256][2048] f16

    hipLaunchKernelGGL(k_prep, dim3(2450), dim3(256), 0, stream,
                       conv_w, fc_w2_w, emb, Wt, fc2t, Psum, wpack, flagc, emb16);
    hipLaunchKernelGGL(k_branch, dim3(2048), dim3(256), 0, stream,
                       u_rev, i_rev, emb16, wpack, conv_b, fc_w_w, fc_w_b,
                       fc_w2_b, fc2t, h_r_w, h_c_w,
                       Pbuf, Psum, zdotb, Pdotb, out + 40000, flagc, flist);
    hipLaunchKernelGGL(k_refine, dim3(128), dim3(256), 0, stream,
                       u_rev, i_rev, emb, Wt, conv_b, fc_w_w, fc_w_b, h_r_w,
                       flagc, flist, out + 40000, zdotb);
    hipLaunchKernelGGL(k_gmat, dim3(256), dim3(256), 0, stream, Pbuf, Psum, Gbuf);
    hipLaunchKernelGGL(k_edge, dim3(1250), dim3(256), 0, stream,
                       uid, iid, Gbuf, zdotb, Pdotb,
                       user_b, item_b, global_b, out);
}

// Round 7
// 172.178 us; speedup vs baseline: 1.0464x; 1.0464x over previous
//
#include <hip/hip_runtime.h>
#include <hip/hip_fp16.h>
#include <math.h>

// Model: review-based recommender. ALL float tensors fp32.
// Shapes: VOCAB=20000, D=100, H=100, K=3, N_U=N_I=256, R=8, S=52, Sp=50, E=20000.
// Outputs (fp32, flat): pred_r[20000] @0, pred_c[20000] @20000,
//                       z_u[102400] @40000, z_i[102400] @142400.
//
// R21 == R19 byte-exact revert (best measured: 172.4us). R20 post-mortem:
// LDS-shrink/overlay regressed k_branch 43->53us — occupancy FELL to 33-35%
// (prediction falsified), +8192 bank conflicts, WRITE_SIZE tripled. The R16
// k_branch form is a verified local optimum across 5 structural variants.
// R18/19 structure: (a) k_branch/k_prep = R16 (cooperative LDS W staging,
// 2 inst/block, reg-prefetch pipeline); (b) k_gmat = MFMA GEMM (64x64 tiles,
// f16 LDS staging, stride 136) replacing the 420MB L2 re-read version.

typedef __attribute__((ext_vector_type(8))) _Float16 half8;
typedef __attribute__((ext_vector_type(4))) float f32x4;

__device__ __forceinline__ float sigmoidf_(float x) { return 1.f / (1.f + expf(-x)); }
__device__ __forceinline__ ushort f2h(float x) {
    union { __half h; ushort u; } t; t.h = __float2half(x); return t.u;
}
__device__ __forceinline__ float h2f(ushort u) {
    union { __half h; ushort u; } t; t.u = u; return __half2float(t.h);
}

#define Z_MARGIN 4e-4f
#define FLAG_CAP 204800

// ---------------------------------------------------------------------------
// K0: prep: Wt[kk=300][h=100] fp32 (refine); fc2t[h][dd]; zero Psum;
// wpack f16 B-frag layout (verified r10/r11); zero flag cnt; emb -> f16 (x4 vec).
__global__ void k_prep(const float* __restrict__ conv_w, const float* __restrict__ fc_w2_w,
                       const float* __restrict__ emb,
                       float* __restrict__ Wt, float* __restrict__ fc2t,
                       float* __restrict__ Psum, ushort* __restrict__ wpack,
                       int* __restrict__ flag_cnt, ushort* __restrict__ emb16) {
    int idx = blockIdx.x * 256 + threadIdx.x;
    if (idx < 30000) {
        int kk = idx / 100, h = idx - kk * 100;
        Wt[idx] = conv_w[h * 300 + kk];
    } else if (idx < 40000) {
        int j = idx - 30000;
        int h = j / 100, dd = j - h * 100;
        fc2t[j] = fc_w2_w[dd * 100 + h];
    } else if (idx < 91200) {
        Psum[idx - 40000] = 0.f;
    } else if (idx < 127040) {
        int j = idx - 91200;                   // [0, 35840)
        int frag = j >> 9, within = j & 511;
        int l = within >> 3, jj = within & 7;
        int kt = frag / 7, nt = frag % 7;
        int kk = kt * 32 + ((l >> 4) << 3) + jj;
        int h  = nt * 16 + (l & 15);
        wpack[j] = (kk < 300 && h < 100) ? f2h(conv_w[h * 300 + kk]) : (ushort)0;
    } else if (idx == 127040) {
        *flag_cnt = 0;
    } else {
        int j = idx - 127041;                  // [0, 500000) float4 groups
        if (j < 500000) {
            float4 v = ((const float4*)emb)[j];
            uint2 o;
            o.x = (unsigned)f2h(v.x) | ((unsigned)f2h(v.y) << 16);
            o.y = (unsigned)f2h(v.z) | ((unsigned)f2h(v.w) << 16);
            ((uint2*)emb16)[j] = o;
        }
    }
}

// ---------------------------------------------------------------------------
// K1: 2 instances per block (grid 2048), 256 threads = 4 waves, wave = m-tile
// for BOTH instances. Cooperative LDS W staging (R14 pipeline); each B frag
// ds_read feeds acc0 and acc1. (byte-exact R16)
__global__ __launch_bounds__(256, 4)
void k_branch(const int* __restrict__ u_rev, const int* __restrict__ i_rev,
              const ushort* __restrict__ emb16, const ushort* __restrict__ wpack,
              const float* __restrict__ conv_b, const float* __restrict__ fc_w_w,
              const float* __restrict__ fc_w_b, const float* __restrict__ fc_w2_b,
              const float* __restrict__ fc2t, const float* __restrict__ h_r_w,
              const float* __restrict__ h_c_w,
              float* __restrict__ Pbuf, float* __restrict__ Psum,
              float* __restrict__ zdot, float* __restrict__ Pdot,
              float* __restrict__ z_out, int* __restrict__ flag_cnt,
              int* __restrict__ flag_list) {
    __shared__ __align__(16) char smem[39840];
    ushort* xw    = (ushort*)smem;                   // [2][6656] f16 X (zero-padded)
    ushort* wbuf  = (ushort*)(smem + 26624);         // [3584] one kt-chunk B-frags
    int*    s_tok = (int*)(smem + 33792);            // [2][52]
    float*  s_vmax= (float*)(smem + 34208);          // [2][4][100]
    float*  s_maxf= (float*)(smem + 37408);          // [2][100]
    float*  s_z   = (float*)(smem + 38208);          // [2][52]
    float*  s_lg  = (float*)(smem + 38624);          // [2][52]
    float*  s_P   = (float*)(smem + 39040);          // [2][100]

    const int tid = threadIdx.x, lane = tid & 63, w = tid >> 6;
    const int b = blockIdx.x;
    const int branch = b >> 10, pair = b & 1023;
    const int inst0 = pair * 2;

    const uint4* wp4 = (const uint4*)wpack;
    uint4* wbuf4 = (uint4*)wbuf;
    uint4 st0 = wp4[tid];
    uint4 st1; if (tid < 192) st1 = wp4[256 + tid];

    const int* rev = branch ? i_rev : u_rev;
    if (tid < 104) {
        int ii = tid >= 52, s = tid - ii * 52;
        s_tok[tid] = rev[(inst0 + ii) * 52 + s];
    }
    __syncthreads();

    {
        const uint2* emb2 = (const uint2*)emb16;
        uint2 v[11];
#pragma unroll
        for (int k = 0; k < 11; k++) {
            int idx = tid + (k << 8);
            if (idx < 2600) {
                int ii = idx >= 1300;
                int within = idx - ii * 1300;
                int s = within / 25, c = within - s * 25;
                v[k] = emb2[s_tok[ii * 52 + s] * 25 + c];
            }
        }
#pragma unroll
        for (int k = 0; k < 11; k++) {
            int idx = tid + (k << 8);
            if (idx < 2600) {
                int ii = idx >= 1300;
                int within = idx - ii * 1300;
                *(uint2*)(xw + ii * 6656 + within * 4) = v[k];
            }
        }
        uint4 z4; z4.x = 0u; z4.y = 0u; z4.z = 0u; z4.w = 0u;
        for (int t2 = tid; t2 < 364; t2 += 256) {
            int ii = t2 >= 182, off = t2 - ii * 182;
            ((uint4*)xw)[ii * 832 + 650 + off] = z4;
        }
    }

    wbuf4[tid] = st0;
    if (tid < 192) wbuf4[256 + tid] = st1;
    st0 = wp4[448 + tid];
    if (tid < 192) st1 = wp4[448 + 256 + tid];
    __syncthreads();

    f32x4 acc0[7], acc1[7];
#pragma unroll
    for (int nt = 0; nt < 7; nt++) {
        acc0[nt] = (f32x4){0.f, 0.f, 0.f, 0.f};
        acc1[nt] = (f32x4){0.f, 0.f, 0.f, 0.f};
    }

    const int col = lane & 15, quad = lane >> 4, q8 = quad << 3;
    const int mt = w;

    for (int kt = 0; kt < 10; kt++) {
        {
            int e0 = (mt * 16 + col) * 100 + kt * 32 + q8;
            union AU { half8 h8; uint2 u2[2]; } a0, a1;
            a0.u2[0] = *(const uint2*)(xw + e0);
            a0.u2[1] = *(const uint2*)(xw + e0 + 4);
            a1.u2[0] = *(const uint2*)(xw + 6656 + e0);
            a1.u2[1] = *(const uint2*)(xw + 6656 + e0 + 4);
#pragma unroll
            for (int nt = 0; nt < 7; nt++) {
                union BU { half8 h8; uint4 u4; } bu;
                bu.u4 = wbuf4[nt * 64 + lane];
                acc0[nt] = __builtin_amdgcn_mfma_f32_16x16x32_f16(a0.h8, bu.h8, acc0[nt], 0, 0, 0);
                acc1[nt] = __builtin_amdgcn_mfma_f32_16x16x32_f16(a1.h8, bu.h8, acc1[nt], 0, 0, 0);
            }
        }
        __syncthreads();
        if (kt < 9) {
            wbuf4[tid] = st0;
            if (tid < 192) wbuf4[256 + tid] = st1;
            if (kt < 8) {
                st0 = wp4[(kt + 2) * 448 + tid];
                if (tid < 192) st1 = wp4[(kt + 2) * 448 + 256 + tid];
            }
            __syncthreads();
        }
    }

    // epilogue. C/D layout: n=col, m-row = quad*4+j [r6-r11 verified].
    float cb[7], fw[7];
#pragma unroll
    for (int nt = 0; nt < 7; nt++) {
        int h = nt * 16 + col;
        cb[nt] = (h < 100) ? conv_b[h] : 0.f;
        fw[nt] = (h < 100) ? fc_w_w[h] : 0.f;
    }
    const float fcb = fc_w_b[0];

#define EPILOGUE_MM(II, ACC)                                                   \
    {                                                                          \
        float vmax[7];                                                         \
        _Pragma("unroll") for (int nt = 0; nt < 7; nt++) vmax[nt] = 0.f;       \
        _Pragma("unroll")                                                      \
        for (int j = 0; j < 4; j++) {                                          \
            int p = mt * 16 + quad * 4 + j;                                    \
            bool pv = p < 50;                                                  \
            float part = 0.f;                                                  \
            _Pragma("unroll")                                                  \
            for (int nt = 0; nt < 7; nt++) {                                   \
                float c = ACC[nt][j] + cb[nt];                                 \
                c = c > 0.f ? c : 0.f;                                         \
                part += c * fw[nt];                                            \
                if (pv) vmax[nt] = fmaxf(vmax[nt], c);                         \
            }                                                                  \
            part += __shfl_xor(part, 1, 64);                                   \
            part += __shfl_xor(part, 2, 64);                                   \
            part += __shfl_xor(part, 4, 64);                                   \
            part += __shfl_xor(part, 8, 64);                                   \
            if (pv && col == 0) {                                              \
                float logit = part + fcb;                                      \
                float z = rintf(sigmoidf_(logit));                             \
                s_z[(II) * 52 + p] = z;                                        \
                s_lg[(II) * 52 + p] = logit;                                   \
                z_out[branch * 102400 + (inst0 + (II)) * 50 + p] = z;          \
            }                                                                  \
        }                                                                      \
        _Pragma("unroll")                                                      \
        for (int nt = 0; nt < 7; nt++) {                                       \
            float m = vmax[nt];                                                \
            m = fmaxf(m, __shfl_xor(m, 16, 64));                               \
            m = fmaxf(m, __shfl_xor(m, 32, 64));                               \
            int h = nt * 16 + col;                                             \
            if (quad == 0 && h < 100) s_vmax[(II) * 400 + w * 100 + h] = m;    \
        }                                                                      \
    }

    EPILOGUE_MM(0, acc0)
    EPILOGUE_MM(1, acc1)
#undef EPILOGUE_MM
    __syncthreads();

    if (tid < 200) {
        int ii = tid >= 100, h = tid - ii * 100;
        const float* sv = s_vmax + ii * 400;
        float mx = fmaxf(fmaxf(sv[h], sv[100 + h]),
                         fmaxf(sv[200 + h], sv[300 + h]));
        s_maxf[ii * 100 + h] = mx;
    }
    __syncthreads();

    if (tid < 200) {
        int ii = tid >= 100, dd = tid - ii * 100;
        float a = fc_w2_b[dd];
        for (int h0 = 0; h0 < 100; h0 += 10) {
            float wv[10], mxv[10];
#pragma unroll
            for (int t = 0; t < 10; t++) {
                wv[t] = fc2t[(h0 + t) * 100 + dd];
                mxv[t] = s_maxf[ii * 100 + h0 + t];
            }
#pragma unroll
            for (int t = 0; t < 10; t++) a += mxv[t] * wv[t];
        }
        int inst = inst0 + ii;
        int gi = branch * 2048 + inst;
        Pbuf[gi * 100 + dd] = a;
        s_P[ii * 100 + dd] = a;
        atomicAdd(&Psum[(branch * 256 + (inst >> 3)) * 100 + dd], a);
    }
    __syncthreads();

    if (w == 0) {
#pragma unroll
        for (int ii = 0; ii < 2; ii++) {
            float v = (lane < 50) ? s_z[ii * 52 + lane] * h_r_w[branch * 50 + lane] : 0.f;
            for (int s = 1; s < 64; s <<= 1) v += __shfl_xor(v, s, 64);
            if (lane == 0) zdot[branch * 2048 + inst0 + ii] = v;
        }
    } else if (w == 1) {
#pragma unroll
        for (int ii = 0; ii < 2; ii++) {
            float u = 0.f;
            if (lane < 50) u = s_P[ii * 100 + lane] * h_c_w[branch * 100 + lane]
                             + s_P[ii * 100 + lane + 50] * h_c_w[branch * 100 + lane + 50];
            for (int s = 1; s < 64; s <<= 1) u += __shfl_xor(u, s, 64);
            if (lane == 0) Pdot[branch * 2048 + inst0 + ii] = u;
        }
    } else {
        int ii = w - 2;                       // w==2 -> inst0, w==3 -> inst0+1
        float lg = 1e9f;
        if (lane < 50) lg = s_lg[ii * 52 + lane];
        unsigned long long mb = __ballot(fabsf(lg) < Z_MARGIN);
        int cnt = __popcll(mb);
        int base = 0;
        if (lane == 0 && cnt) base = atomicAdd(flag_cnt, cnt);
        base = __shfl(base, 0, 64);
        if (fabsf(lg) < Z_MARGIN) {
            int rank = __popcll(mb & ((1ull << lane) - 1ull));
            int k = base + rank;
            if (k < FLAG_CAP) flag_list[k] = (branch * 2048 + inst0 + ii) * 50 + lane;
        }
    }
}

// ---------------------------------------------------------------------------
// K2: exact fp32 recompute of flagged z-logits (identical to r14-r19).
__launch_bounds__(256)
__global__ void k_refine(const int* __restrict__ u_rev, const int* __restrict__ i_rev,
                         const float* __restrict__ emb, const float* __restrict__ Wt,
                         const float* __restrict__ conv_b, const float* __restrict__ fc_w_w,
                         const float* __restrict__ fc_w_b, const float* __restrict__ h_r_w,
                         const int* __restrict__ flag_cnt, const int* __restrict__ flag_list,
                         float* __restrict__ z_out, float* __restrict__ zdot) {
    int n = *flag_cnt; if (n > FLAG_CAP) n = FLAG_CAP;
    const int lane = threadIdx.x & 63;
    const int wid = (blockIdx.x * 256 + threadIdx.x) >> 6;
    const int nw = gridDim.x * 4;
    const bool hv = lane < 50;
    const float cb0 = hv ? conv_b[lane] : 0.f;
    const float cb1 = hv ? conv_b[lane + 50] : 0.f;
    const float fw0 = hv ? fc_w_w[lane] : 0.f;
    const float fw1 = hv ? fc_w_w[lane + 50] : 0.f;
    const float fcb = fc_w_b[0];

    for (int e0 = wid * 4; e0 < n; e0 += nw * 4) {
        int gi[4], pos[4];
        bool iv[4];
        float xr[4][5];
#pragma unroll
        for (int m = 0; m < 4; m++) {
            int e = e0 + m;
            iv[m] = e < n;
            int code = iv[m] ? flag_list[e] : 0;
            gi[m] = code / 50; pos[m] = code - gi[m] * 50;
            const int* rev = (gi[m] >> 11) ? i_rev : u_rev;
            int tb = (gi[m] & 2047) * 52 + pos[m];
            int t0 = rev[tb], t1 = rev[tb + 1], t2 = rev[tb + 2];
#pragma unroll
            for (int s = 0; s < 5; s++) {
                int k = s * 64 + lane;
                float v = 0.f;
                if (k < 300) {
                    int r = k / 100, dd = k - r * 100;
                    int t = (r == 0) ? t0 : ((r == 1) ? t1 : t2);
                    v = emb[t * 100 + dd];
                }
                xr[m][s] = v;
            }
        }
        float c0[4], c1[4];
#pragma unroll
        for (int m = 0; m < 4; m++) { c0[m] = cb0; c1[m] = cb1; }
        for (int s = 0; s < 5; s++) {
            const int dmax = (s < 4) ? 64 : 44;
            for (int db = 0; db < dmax; db += 16) {
                const int cnt = (dmax - db < 16) ? (dmax - db) : 16;
                float w0a[16], w1a[16];
#pragma unroll
                for (int t = 0; t < 16; t++) {
                    int d = s * 64 + db + t;
                    bool on = (t < cnt) && hv;          // masked: OOB lanes load 0
                    w0a[t] = on ? Wt[d * 100 + lane] : 0.f;
                    w1a[t] = on ? Wt[d * 100 + lane + 50] : 0.f;
                }
#pragma unroll
                for (int t = 0; t < 16; t++) {          // w==0 beyond cnt -> adds 0
#pragma unroll
                    for (int m = 0; m < 4; m++) {
                        float x = __shfl(xr[m][s], db + t, 64);
                        c0[m] += x * w0a[t];
                        c1[m] += x * w1a[t];
                    }
                }
            }
        }
#pragma unroll
        for (int m = 0; m < 4; m++) {
            float v = fmaxf(c0[m], 0.f) * fw0 + fmaxf(c1[m], 0.f) * fw1;
            for (int s = 1; s < 64; s <<= 1) v += __shfl_xor(v, s, 64);
            if (lane == 0 && iv[m]) {
                int branch = gi[m] >> 11, inst = gi[m] & 2047;
                float z = rintf(sigmoidf_(v + fcb));
                float old = z_out[branch * 102400 + inst * 50 + pos[m]];
                if (z != old) {
                    z_out[branch * 102400 + inst * 50 + pos[m]] = z;
                    atomicAdd(&zdot[gi[m]], (z - old) * h_r_w[branch * 50 + pos[m]]);
                }
            }
        }
    }
}

// ---------------------------------------------------------------------------
// K3 (R18): G as MFMA GEMM. G_s[i][j] = dot(PsumSide_s[i], Pbuf_s[j]),
// i in [0,256), j in [0,2048), K=100 (padded 128 with zeros).
// Grid 256: b -> s = b>>7, it = (b>>5)&3 (64 i-rows), jt = b&31 (64 j-rows).
// Both operands f32->f16 into LDS [64][136] (stride 136 breaks pow2 banks),
// then 4 waves x (4 kt x 4 nt) MFMA, D layout n=col / m=quad*4+jj (verified).
__launch_bounds__(256)
__global__ void k_gmat(const float* __restrict__ Pbuf, const float* __restrict__ Psum,
                       ushort* __restrict__ G) {
    __shared__ __align__(16) ushort Af[64 * 136];   // Psum side (i rows)
    __shared__ __align__(16) ushort Bf[64 * 136];   // Pbuf side (j rows)

    const int tid = threadIdx.x, lane = tid & 63, w = tid >> 6;
    const int b = blockIdx.x;
    const int s = b >> 7, it = (b >> 5) & 3, jt = b & 31;
    const int ibase = it * 64, jbase = jt * 64;

    const float4* psum4 = (const float4*)(Psum + (s == 0 ? 25600 : 0) + ibase * 100);
    const float4* pbuf4 = (const float4*)(Pbuf + (s * 2048 + jbase) * 100);

    // stage: 2 tiles x 64 rows x 25 float4 -> f16 LDS (cols 0..100)
    for (int g = tid; g < 3200; g += 256) {
        int side = g >= 1600, within = g - side * 1600;
        int r = within / 25, c4 = within - r * 25;
        float4 v = side ? pbuf4[r * 25 + c4] : psum4[r * 25 + c4];
        uint2 o;
        o.x = (unsigned)f2h(v.x) | ((unsigned)f2h(v.y) << 16);
        o.y = (unsigned)f2h(v.z) | ((unsigned)f2h(v.w) << 16);
        ushort* dst = (side ? Bf : Af) + r * 136 + c4 * 4;
        *(uint2*)dst = o;
    }
    // zero pad cols 100..128 (read by kt=3), both tiles
    for (int t = tid; t < 896; t += 256) {
        int side = t >= 448, within = t - side * 448;
        int r = within / 7, k = within - r * 7;
        ushort* dst = (side ? Bf : Af) + r * 136 + 100 + k * 4;
        *(uint2*)dst = (uint2){0u, 0u};
    }
    __syncthreads();

    const int col = lane & 15, quad = lane >> 4, q8 = quad << 3;

    f32x4 acc[4];
#pragma unroll
    for (int nt = 0; nt < 4; nt++) acc[nt] = (f32x4){0.f, 0.f, 0.f, 0.f};

#pragma unroll
    for (int kt = 0; kt < 4; kt++) {
        union FU { half8 h8; uint4 u4; } a;
        a.u4 = *(const uint4*)(Af + (w * 16 + col) * 136 + kt * 32 + q8);
#pragma unroll
        for (int nt = 0; nt < 4; nt++) {
            union FU bu;
            bu.u4 = *(const uint4*)(Bf + (nt * 16 + col) * 136 + kt * 32 + q8);
            acc[nt] = __builtin_amdgcn_mfma_f32_16x16x32_f16(a.h8, bu.h8, acc[nt], 0, 0, 0);
        }
    }

    // D layout: n (j within 16) = col, m (i within 16) = quad*4+jj
    ushort* Gs = G + s * 524288;
#pragma unroll
    for (int nt = 0; nt < 4; nt++) {
#pragma unroll
        for (int jj = 0; jj < 4; jj++) {
            int gi_row = ibase + w * 16 + quad * 4 + jj;
            int gj = jbase + nt * 16 + col;
            Gs[gi_row * 2048 + gj] = f2h(acc[nt][jj]);
        }
    }
}

// ---------------------------------------------------------------------------
// K4: per-edge, O(1) reads (identical to r11-r19).
__launch_bounds__(256)
__global__ void k_edge(const int* __restrict__ uid, const int* __restrict__ iid,
                       const ushort* __restrict__ G,
                       const float* __restrict__ zdot, const float* __restrict__ Pdot,
                       const float* __restrict__ user_bias, const float* __restrict__ item_bias,
                       const float* __restrict__ global_bias, float* __restrict__ out) {
    const int tid = threadIdx.x, lane = tid & 63, w = tid >> 6;
    const int e = blockIdx.x * 16 + w * 4 + (lane >> 4);
    const int r = lane & 15;
    int u = uid[e], i = iid[e];
    float gv, wr, wc;
    if (r < 8) {
        gv = h2f(G[i * 2048 + u * 8 + r]);
        wr = zdot[u * 8 + r]; wc = Pdot[u * 8 + r];
    } else {
        int a = r - 8;
        gv = h2f(G[524288 + u * 2048 + i * 8 + a]);
        wr = zdot[2048 + i * 8 + a]; wc = Pdot[2048 + i * 8 + a];
    }
    float sg = sigmoidf_(gv);
    float cr = sg * wr, cc = sg * wc;
    cr += __shfl_xor(cr, 1, 64); cc += __shfl_xor(cc, 1, 64);
    cr += __shfl_xor(cr, 2, 64); cc += __shfl_xor(cc, 2, 64);
    cr += __shfl_xor(cr, 4, 64); cc += __shfl_xor(cc, 4, 64);
    cr += __shfl_xor(cr, 8, 64); cc += __shfl_xor(cc, 8, 64);
    if (r == 0) {
        out[e] = cr + user_bias[u] + item_bias[i] + global_bias[0];
        out[20000 + e] = cc;
    }
}

// ---------------------------------------------------------------------------
extern "C" void kernel_launch(void* const* d_in, const int* in_sizes, int n_in,
                              void* d_out, int out_size, void* d_ws, size_t ws_size,
                              hipStream_t stream) {
    const int*   u_rev    = (const int*)d_in[0];
    const int*   i_rev    = (const int*)d_in[1];
    const int*   uid      = (const int*)d_in[2];
    const int*   iid      = (const int*)d_in[3];
    const float* emb      = (const float*)d_in[4];
    const float* conv_w   = (const float*)d_in[5];
    const float* conv_b   = (const float*)d_in[6];
    const float* fc_w_w   = (const float*)d_in[7];
    const float* fc_w_b   = (const float*)d_in[8];
    const float* fc_w2_w  = (const float*)d_in[9];
    const float* fc_w2_b  = (const float*)d_in[10];
    const float* h_r_w    = (const float*)d_in[11];
    const float* h_c_w    = (const float*)d_in[12];
    const float* user_b   = (const float*)d_in[13];
    const float* item_b   = (const float*)d_in[14];
    const float* global_b = (const float*)d_in[15];
    float* out = (float*)d_out;

    float*  ws    = (float*)d_ws;
    float*  Pbuf  = ws;                       // [409600]
    float*  Psum  = ws + 409600;              // [51200]
    float*  zdotb = ws + 460800;              // [4096]
    float*  Pdotb = ws + 464896;              // [4096]
    float*  Wt    = ws + 468992;              // [30000]
    float*  fc2t  = ws + 498992;              // [10000]
    ushort* wpack = (ushort*)(ws + 508992);   // [35840] f16
    int*    flagc = (int*)(ws + 526912);      // [1]
    int*    flist = (int*)(ws + 526916);      // [204800]
    ushort* emb16 = (ushort*)(ws + 731716);   // [2,000,000] f16
    ushort* Gbuf  = (ushort*)(ws + 1731716);  // [2][256][2048] f16

    hipLaunchKernelGGL(k_prep, dim3(2450), dim3(256), 0, stream,
                       conv_w, fc_w2_w, emb, Wt, fc2t, Psum, wpack, flagc, emb16);
    hipLaunchKernelGGL(k_branch, dim3(2048), dim3(256), 0, stream,
                       u_rev, i_rev, emb16, wpack, conv_b, fc_w_w, fc_w_b,
                       fc_w2_b, fc2t, h_r_w, h_c_w,
                       Pbuf, Psum, zdotb, Pdotb, out + 40000, flagc, flist);
    hipLaunchKernelGGL(k_refine, dim3(128), dim3(256), 0, stream,
                       u_rev, i_rev, emb, Wt, conv_b, fc_w_w, fc_w_b, h_r_w,
                       flagc, flist, out + 40000, zdotb);
    hipLaunchKernelGGL(k_gmat, dim3(256), dim3(256), 0, stream, Pbuf, Psum, Gbuf);
    hipLaunchKernelGGL(k_edge, dim3(1250), dim3(256), 0, stream,
                       uid, iid, Gbuf, zdotb, Pdotb,
                       user_b, item_b, global_b, out);
}